// Round 7
// baseline (563.533 us; speedup 1.0000x reference)
//
#include <hip/hip_runtime.h>
#include <hip/hip_bf16.h>

// Problem constants (fixed by reference setup_inputs)
#define B_ROWS 8192
#define D_DIM  768

// Main-kernel tile config: 128(I) x 256(J) block tile, K-step 64 (fp8),
// 512 threads = 8 waves (2 wm x 4 wn), each wave owns a 64x64 output tile
// = 2x2 frags of 32x32; MX-scaled mfma_scale_f32_32x32x64_f8f6f4 (scale=1.0).
#define BI 128
#define BJ 256
#define BK 64
#define NTHREADS 512
#define KTILES (D_DIM / BK)            // 12
#define TILE_BYTES (128 * BK)          // 8192 B per fp8 panel-tile (128 rows x 64B)
#define PANEL_BYTES ((size_t)B_ROWS * (size_t)D_DIM)   // 6291456 B (fp8)

// LDS byte offsets: F(8192) FM2(8192) M2(8192) BF(16384) BF2(16384)
#define LDS_F    0
#define LDS_FM2  8192
#define LDS_M2   16384
#define LDS_BF   24576
#define LDS_BF2  40960
#define LDSBUF_BYTES 57344             // x2 = 114688 B

// Quartet-clean swizzle key (period 32 in row): rows r and r+16 get different
// keys -> lanes {l,l+16,l+32,l+48} hit 4 distinct bank-quads (R5 fix).
#define S2(r) (((((r) >> 1) & 3)) ^ ((((r) >> 4) & 1)))

typedef __attribute__((ext_vector_type(8))) short bf16x8;           // bf16 frag (fallback)
typedef __attribute__((ext_vector_type(8))) unsigned short u16x8;   // 16B vector store
typedef __attribute__((ext_vector_type(4))) float f32x4;            // 16x16 C/D frag
typedef __attribute__((ext_vector_type(16))) float f32x16;          // 32x32 C/D frag
typedef __attribute__((ext_vector_type(4))) int i32x4;              // 16B LDS read
typedef __attribute__((ext_vector_type(8))) int i32x8;              // 32B MX A/B frag

__device__ __forceinline__ i32x8 mk8(i32x4 lo, i32x4 hi) {
  return __builtin_shufflevector(lo, hi, 0, 1, 2, 3, 4, 5, 6, 7);
}

__device__ __forceinline__ unsigned short f2bf(float x) {
  unsigned int u = __float_as_uint(x);
  u += 0x7fffu + ((u >> 16) & 1u);
  return (unsigned short)(u >> 16);
}

// fp32 -> OCP e4m3fn, round-to-nearest-even, saturate to 448.
__device__ __forceinline__ unsigned int f2fp8(float x) {
  unsigned int u = __float_as_uint(x);
  unsigned int s = (u >> 24) & 0x80u;
  unsigned int au = u & 0x7FFFFFFFu;
  if (au < 0x3C800000u) {                  // |x| < 2^-6: fp8-subnormal region
    int k = (int)rintf(__uint_as_float(au) * 512.0f);   // multiples of 2^-9
    return s | (unsigned int)k;            // k==8 rolls into smallest normal
  }
  unsigned int m = au & 0x7FFFFFu;
  unsigned int e = au >> 23;               // >= 121
  unsigned int keep = m >> 20;
  unsigned int rest = m & 0xFFFFFu;
  keep += (rest > 0x80000u) || (rest == 0x80000u && (keep & 1u));
  unsigned int v = ((e - 120u) << 3) + keep;   // carry from keep ok
  if (v > 0x7Eu) v = 0x7Eu;                // clamp to 448
  return s | v;
}

__device__ __forceinline__ float4 f4mul(float4 a, float4 b) {
  return make_float4(a.x * b.x, a.y * b.y, a.z * b.z, a.w * b.w);
}

__device__ __forceinline__ u16x8 cvt8(float4 a, float4 b) {
  u16x8 v;
  v[0] = f2bf(a.x); v[1] = f2bf(a.y); v[2] = f2bf(a.z); v[3] = f2bf(a.w);
  v[4] = f2bf(b.x); v[5] = f2bf(b.y); v[6] = f2bf(b.z); v[7] = f2bf(b.w);
  return v;
}

__device__ __forceinline__ unsigned long long pack8(float4 a, float4 b) {
  unsigned long long u = 0;
  u |= (unsigned long long)f2fp8(a.x);
  u |= (unsigned long long)f2fp8(a.y) << 8;
  u |= (unsigned long long)f2fp8(a.z) << 16;
  u |= (unsigned long long)f2fp8(a.w) << 24;
  u |= (unsigned long long)f2fp8(b.x) << 32;
  u |= (unsigned long long)f2fp8(b.y) << 40;
  u |= (unsigned long long)f2fp8(b.z) << 48;
  u |= (unsigned long long)f2fp8(b.w) << 56;
  return u;
}

// Direct global->LDS async copy, 16B per lane (wave-uniform LDS base + lane*16).
__device__ __forceinline__ void gload16(const void* g, void* l) {
  __builtin_amdgcn_global_load_lds(
      (const __attribute__((address_space(1))) unsigned int*)(uintptr_t)g,
      (__attribute__((address_space(3))) unsigned int*)(unsigned int)(uintptr_t)l,
      16, 0, 0);
}

// Pre-pass: fp32 inputs -> four e4m3 panels, tiled panel[tr][tk][128][64B].
// k is LINEAR within the 64B row; 16B chunks XOR-swizzled c' = c ^ S2(row).
// FUSED: rn[r] += sum_d f^2 m^2 (fp32 exact; rn pre-zeroed).
__global__ __launch_bounds__(256) void convert_kernel(
    const float* __restrict__ f, const float* __restrict__ mask,
    unsigned char* __restrict__ pF, unsigned char* __restrict__ pFM2,
    unsigned char* __restrict__ pM2, unsigned char* __restrict__ pF2,
    float* __restrict__ rn) {
  const int g = blockIdx.x * 256 + threadIdx.x;   // 8192*96 chunks of 8 elems
  const int r = g / (D_DIM / 8);
  const int chunk = g - r * (D_DIM / 8);          // 0..95
  const float* fr = f + (size_t)r * D_DIM + chunk * 8;
  const float* mr = mask + (size_t)r * D_DIM + chunk * 8;
  float4 fv0 = *(const float4*)(fr);
  float4 fv1 = *(const float4*)(fr + 4);
  float4 mv0 = *(const float4*)(mr);
  float4 mv1 = *(const float4*)(mr + 4);
  float4 m20 = f4mul(mv0, mv0), m21 = f4mul(mv1, mv1);
  float4 fm0 = f4mul(fv0, m20), fm1 = f4mul(fv1, m21);
  float4 f20 = f4mul(fv0, fv0), f21 = f4mul(fv1, fv1);

  const int tr = r >> 7, rr = r & 127;
  const int tk = chunk >> 3;                      // K-64 tile 0..11
  const int c8 = chunk & 7;                       // 8B group within 64B row
  const int c  = c8 >> 1;                         // 16B chunk 0..3
  const int h8 = c8 & 1;
  const int cs = c ^ S2(rr);                      // swizzled chunk
  const size_t off = ((size_t)((tr * KTILES + tk) * 128 + rr)) * 64 + cs * 16 + h8 * 8;
  *(unsigned long long*)(pF + off)   = pack8(fv0, fv1);
  *(unsigned long long*)(pFM2 + off) = pack8(fm0, fm1);
  *(unsigned long long*)(pM2 + off)  = pack8(m20, m21);
  *(unsigned long long*)(pF2 + off)  = pack8(f20, f21);

  float s = f20.x * m20.x + f20.y * m20.y + f20.z * m20.z + f20.w * m20.w
          + f21.x * m21.x + f21.y * m21.y + f21.z * m21.z + f21.w * m21.w;
  for (int o = 16; o > 0; o >>= 1) s += __shfl_down(s, o, 32);
  if ((threadIdx.x & 31) == 0) atomicAdd(&rn[r], s);
}

// Main kernel: fused triple-GEMM + loss, MX-fp8 32x32x64 (uniform scale 1.0),
// R3-proven 2-barrier dbuf loop (prefetch before compute, one vmcnt(0)+barrier).
//  accS = f_i . f_j ; accN = (f_i*m2_i) . f_j ; accD = m2_i . f_j^2
__global__ __launch_bounds__(NTHREADS) void fused_loss_mx_kernel(
    const unsigned char* __restrict__ pF, const unsigned char* __restrict__ pFM2,
    const unsigned char* __restrict__ pM2, const unsigned char* __restrict__ pF2,
    const float* __restrict__ rn, float* __restrict__ out) {
  __shared__ unsigned char lds[2 * LDSBUF_BYTES];
  __shared__ float red[8];

  const int t    = threadIdx.x;
  const int lane = t & 63;
  const int wv   = t >> 6;        // wave id 0..7
  const int wm   = wv >> 2;       // 0..1  (row group of 64)
  const int wn   = wv & 3;        // 0..3  (col group of 64)
  const int rl   = lane & 31;     // fragment row within 32-row block
  const int u    = lane >> 5;     // k-half selector (0/1): k = u*32..u*32+31

  const int trA = blockIdx.y;     // i0 = trA*128
  const int trB = blockIdx.x;     // j0 = trB*256 -> panel row-tiles 2trB, 2trB+1
  const int te  = t * 16;         // staging byte offset (16B per thread)

  const size_t baseA  = (size_t)(trA * KTILES) * TILE_BYTES;
  const size_t baseB0 = (size_t)((2 * trB) * KTILES) * TILE_BYTES;
  const size_t baseB1 = (size_t)((2 * trB + 1) * KTILES) * TILE_BYTES;

  // Precomputed swizzled ds_read byte offsets: two 16B reads per 32B frag,
  // chunks c = 2u, 2u+1, swizzled by S2(local row).
  int offA0[2], offA1[2], offB0[2], offB1[2];
#pragma unroll
  for (int mt = 0; mt < 2; ++mt) {
    const int r = wm * 64 + mt * 32 + rl;             // 0..127
    offA0[mt] = r * 64 + (((2 * u) ^ S2(r)) << 4);
    offA1[mt] = r * 64 + (((2 * u + 1) ^ S2(r)) << 4);
  }
#pragma unroll
  for (int nt = 0; nt < 2; ++nt) {
    const int rB = wn * 64 + nt * 32 + rl;            // 0..255
    const int rt = rB >> 7, rr = rB & 127;
    offB0[nt] = rt * TILE_BYTES + rr * 64 + (((2 * u) ^ S2(rr)) << 4);
    offB1[nt] = rt * TILE_BYTES + rr * 64 + (((2 * u + 1) ^ S2(rr)) << 4);
  }

  f32x16 accS[2][2], accN[2][2], accD[2][2];
#pragma unroll
  for (int mt = 0; mt < 2; ++mt)
#pragma unroll
    for (int nt = 0; nt < 2; ++nt)
#pragma unroll
      for (int r = 0; r < 16; ++r) {
        accS[mt][nt][r] = 0.f;
        accN[mt][nt][r] = 0.f;
        accD[mt][nt][r] = 0.f;
      }

#define STAGE(b, tk)                                                          \
  do {                                                                        \
    const size_t _tA  = baseA  + (size_t)(tk) * TILE_BYTES + te;              \
    const size_t _tB0 = baseB0 + (size_t)(tk) * TILE_BYTES + te;              \
    const size_t _tB1 = baseB1 + (size_t)(tk) * TILE_BYTES + te;              \
    gload16(pF   + _tA,  (b) + LDS_F   + te);                                 \
    gload16(pFM2 + _tA,  (b) + LDS_FM2 + te);                                 \
    gload16(pM2  + _tA,  (b) + LDS_M2  + te);                                 \
    gload16(pF   + _tB0, (b) + LDS_BF  + te);                                 \
    gload16(pF   + _tB1, (b) + LDS_BF  + TILE_BYTES + te);                    \
    gload16(pF2  + _tB0, (b) + LDS_BF2 + te);                                 \
    gload16(pF2  + _tB1, (b) + LDS_BF2 + TILE_BYTES + te);                    \
  } while (0)

  unsigned char* const buf0 = lds;
  unsigned char* const buf1 = lds + LDSBUF_BYTES;

  STAGE(buf0, 0);
  asm volatile("s_waitcnt vmcnt(0)" ::: "memory");
  __syncthreads();

  int cur = 0;
  for (int tk = 0; tk < KTILES; ++tk) {
    unsigned char* const cb = cur ? buf1 : buf0;
    unsigned char* const nb = cur ? buf0 : buf1;
    if (tk + 1 < KTILES) STAGE(nb, tk + 1);   // prefetch issued BEFORE compute

    i32x8 bF[2], bF2[2];
#pragma unroll
    for (int nt = 0; nt < 2; ++nt) {
      bF[nt]  = mk8(*(const i32x4*)(cb + LDS_BF  + offB0[nt]),
                    *(const i32x4*)(cb + LDS_BF  + offB1[nt]));
      bF2[nt] = mk8(*(const i32x4*)(cb + LDS_BF2 + offB0[nt]),
                    *(const i32x4*)(cb + LDS_BF2 + offB1[nt]));
    }
#pragma unroll
    for (int mt = 0; mt < 2; ++mt) {
      i32x8 aF = mk8(*(const i32x4*)(cb + LDS_F   + offA0[mt]),
                     *(const i32x4*)(cb + LDS_F   + offA1[mt]));
      i32x8 aN = mk8(*(const i32x4*)(cb + LDS_FM2 + offA0[mt]),
                     *(const i32x4*)(cb + LDS_FM2 + offA1[mt]));
      i32x8 aD = mk8(*(const i32x4*)(cb + LDS_M2  + offA0[mt]),
                     *(const i32x4*)(cb + LDS_M2  + offA1[mt]));
#pragma unroll
      for (int nt = 0; nt < 2; ++nt) {
        // (a, b, c, cbsz=0:fp8, blgp=0:fp8, opselA, scaleA=127(=1.0), opselB, scaleB)
        accS[mt][nt] = __builtin_amdgcn_mfma_scale_f32_32x32x64_f8f6f4(
            aF, bF[nt],  accS[mt][nt], 0, 0, 0, 127, 0, 127);
        accN[mt][nt] = __builtin_amdgcn_mfma_scale_f32_32x32x64_f8f6f4(
            aN, bF[nt],  accN[mt][nt], 0, 0, 0, 127, 0, 127);
        accD[mt][nt] = __builtin_amdgcn_mfma_scale_f32_32x32x64_f8f6f4(
            aD, bF2[nt], accD[mt][nt], 0, 0, 0, 127, 0, 127);
      }
    }
    asm volatile("s_waitcnt vmcnt(0)" ::: "memory");
    __syncthreads();
    cur ^= 1;
  }
#undef STAGE

  // ---- epilogue: pointwise loss + off-diagonal masked reduction ----
  // 32x32 C/D layout (m74/m101-verified, dtype/shape-determined): col = lane&31,
  // row = (reg&3) + 8*(reg>>2) + 4*(lane>>5)   [R5: passed absmax]
  float sum = 0.f;
  const int i0 = trA * BI;
  const int j0 = trB * BJ;
  const int rhi = u * 4;
#pragma unroll
  for (int mt = 0; mt < 2; ++mt) {
#pragma unroll
    for (int r = 0; r < 16; ++r) {
      const int row = (r & 3) + 8 * (r >> 2) + rhi;
      const int gi = i0 + wm * 64 + mt * 32 + row;
      // rn holds sum_d f^2 m^2 ; 1/max(sqrt(s),1e-12) == rsqrt(max(s,1e-24))
      const float rni = rsqrtf(fmaxf(rn[gi], 1e-24f));
#pragma unroll
      for (int nt = 0; nt < 2; ++nt) {
        const int gj = j0 + wn * 64 + nt * 32 + rl;
        const float sfull = accS[mt][nt][r];
        const float num   = accN[mt][nt][r];
        const float nd    = accD[mt][nt][r];
        const float rnij  = rsqrtf(fmaxf(nd, 1e-24f));
        const float sim   = num * rni * rnij;
        const float d     = fabsf(sfull - sim);
        if (gi != gj) sum += d;
      }
    }
  }
  for (int off = 32; off > 0; off >>= 1) sum += __shfl_down(sum, off);
  if (lane == 0) red[wv] = sum;
  __syncthreads();
  if (t == 0) {
    float bs = 0.f;
    for (int w = 0; w < 8; ++w) bs += red[w];
    const float scale = 1.0f / (8192.0f * 8191.0f);
    atomicAdd(out, bs * scale);
  }
}

// ---------------- Fallback path (ws too small): round-1 kernels ---------------
__global__ __launch_bounds__(256) void rownorm_zero_kernel(
    const float* __restrict__ f, const float* __restrict__ mask,
    float* __restrict__ rn_i, float* __restrict__ out) {
  if (blockIdx.x == 0 && threadIdx.x == 0) out[0] = 0.0f;
  const int wv = threadIdx.x >> 6;
  const int lane = threadIdx.x & 63;
  const int row = blockIdx.x * 4 + wv;
  const float* fr = f + (size_t)row * D_DIM;
  const float* mr = mask + (size_t)row * D_DIM;
  float s = 0.f;
  for (int d = lane; d < D_DIM; d += 64) {
    float v = fr[d] * mr[d];
    s += v * v;
  }
  for (int off = 32; off > 0; off >>= 1) s += __shfl_down(s, off);
  if (lane == 0) rn_i[row] = 1.0f / fmaxf(sqrtf(s), 1e-12f);
}

__global__ __launch_bounds__(NTHREADS, 2) void fused_loss_kernel(
    const float* __restrict__ f, const float* __restrict__ mask,
    const float* __restrict__ rn_i, float* __restrict__ out) {
  __shared__ unsigned short sF[128][32];
  __shared__ unsigned short sFM2[128][32];
  __shared__ unsigned short sM2[128][32];
  __shared__ unsigned short sBF[128][32];
  __shared__ unsigned short sBF2[128][32];
  __shared__ float red[8];

  const int t    = threadIdx.x;
  const int lane = t & 63;
  const int wv   = t >> 6;
  const int wm   = wv >> 2;
  const int wn   = wv & 3;
  const int frg  = lane & 15;
  const int ko   = (lane >> 4) * 8;

  const int i0 = blockIdx.y * 128;
  const int j0 = blockIdx.x * 128;
  const int ar = t >> 2;
  const int ac = (t & 3) * 8;

  f32x4 accS[4][2], accN[4][2], accD[4][2];
  for (int m = 0; m < 4; ++m)
    for (int n = 0; n < 2; ++n) {
      accS[m][n] = {0.f, 0.f, 0.f, 0.f};
      accN[m][n] = {0.f, 0.f, 0.f, 0.f};
      accD[m][n] = {0.f, 0.f, 0.f, 0.f};
    }

  const float* fA = f    + (size_t)(i0 + ar) * D_DIM + ac;
  const float* mA = mask + (size_t)(i0 + ar) * D_DIM + ac;
  const float* fB = f    + (size_t)(j0 + ar) * D_DIM + ac;

  for (int k0 = 0; k0 < D_DIM; k0 += 32) {
    __syncthreads();
    float4 fa0 = *(const float4*)(fA + k0);
    float4 fa1 = *(const float4*)(fA + k0 + 4);
    float4 ma0 = *(const float4*)(mA + k0);
    float4 ma1 = *(const float4*)(mA + k0 + 4);
    float4 fb0 = *(const float4*)(fB + k0);
    float4 fb1 = *(const float4*)(fB + k0 + 4);
    float4 m20 = f4mul(ma0, ma0), m21 = f4mul(ma1, ma1);
    float4 fm0 = f4mul(fa0, m20), fm1 = f4mul(fa1, m21);
    float4 f20 = f4mul(fb0, fb0), f21 = f4mul(fb1, fb1);
    *(u16x8*)&sF[ar][ac]   = cvt8(fa0, fa1);
    *(u16x8*)&sFM2[ar][ac] = cvt8(fm0, fm1);
    *(u16x8*)&sM2[ar][ac]  = cvt8(m20, m21);
    *(u16x8*)&sBF[ar][ac]  = cvt8(fb0, fb1);
    *(u16x8*)&sBF2[ar][ac] = cvt8(f20, f21);
    __syncthreads();
    bf16x8 bF[2], bF2[2];
    for (int n = 0; n < 2; ++n) {
      bF[n]  = *(const bf16x8*)&sBF [wn * 32 + n * 16 + frg][ko];
      bF2[n] = *(const bf16x8*)&sBF2[wn * 32 + n * 16 + frg][ko];
    }
#pragma unroll
    for (int m = 0; m < 4; ++m) {
      bf16x8 aF = *(const bf16x8*)&sF  [wm * 64 + m * 16 + frg][ko];
      bf16x8 aN = *(const bf16x8*)&sFM2[wm * 64 + m * 16 + frg][ko];
      bf16x8 aD = *(const bf16x8*)&sM2 [wm * 64 + m * 16 + frg][ko];
#pragma unroll
      for (int n = 0; n < 2; ++n) {
        accS[m][n] = __builtin_amdgcn_mfma_f32_16x16x32_bf16(aF, bF[n],  accS[m][n], 0, 0, 0);
        accN[m][n] = __builtin_amdgcn_mfma_f32_16x16x32_bf16(aN, bF[n],  accN[m][n], 0, 0, 0);
        accD[m][n] = __builtin_amdgcn_mfma_f32_16x16x32_bf16(aD, bF2[n], accD[m][n], 0, 0, 0);
      }
    }
  }

  float sum = 0.f;
  const int r4 = (lane >> 4) * 4;
  const int cc = lane & 15;
#pragma unroll
  for (int m = 0; m < 4; ++m) {
    const int gi_base = i0 + wm * 64 + m * 16 + r4;
#pragma unroll
    for (int jj = 0; jj < 4; ++jj) {
      const int gi = gi_base + jj;
      const float rni = rn_i[gi];
#pragma unroll
      for (int n = 0; n < 2; ++n) {
        const int gj = j0 + wn * 32 + n * 16 + cc;
        const float sfull = accS[m][n][jj];
        const float num   = accN[m][n][jj];
        const float nd    = accD[m][n][jj];
        const float rnij  = rsqrtf(fmaxf(nd, 1e-24f));
        const float sim   = num * rni * rnij;
        const float d     = fabsf(sfull - sim);
        if (gi != gj) sum += d;
      }
    }
  }
  for (int off = 32; off > 0; off >>= 1) sum += __shfl_down(sum, off);
  if (lane == 0) red[wv] = sum;
  __syncthreads();
  if (t == 0) {
    float bs = 0.f;
    for (int w = 0; w < 8; ++w) bs += red[w];
    const float scale = 1.0f / (8192.0f * 8191.0f);
    atomicAdd(out, bs * scale);
  }
}

extern "C" void kernel_launch(void* const* d_in, const int* in_sizes, int n_in,
                              void* d_out, int out_size, void* d_ws, size_t ws_size,
                              hipStream_t stream) {
  const float* f    = (const float*)d_in[0];   // full_emb [8192,768] fp32
  const float* mask = (const float*)d_in[1];   // query_mask [8192,768] fp32
  float* out = (float*)d_out;                  // scalar loss

  const size_t need = 4 * PANEL_BYTES + (size_t)B_ROWS * sizeof(float);
  if (ws_size >= need) {
    unsigned char* pF   = (unsigned char*)d_ws;
    unsigned char* pFM2 = pF + PANEL_BYTES;
    unsigned char* pM2  = pFM2 + PANEL_BYTES;
    unsigned char* pF2  = pM2 + PANEL_BYTES;
    float* rn = (float*)(pF2 + PANEL_BYTES);
    hipMemsetAsync(rn, 0, B_ROWS * sizeof(float), stream);
    hipMemsetAsync(out, 0, sizeof(float), stream);
    convert_kernel<<<(B_ROWS * (D_DIM / 8)) / 256, 256, 0, stream>>>(
        f, mask, pF, pFM2, pM2, pF2, rn);
    dim3 grid(B_ROWS / BJ, B_ROWS / BI);   // 32 x 64
    fused_loss_mx_kernel<<<grid, NTHREADS, 0, stream>>>(pF, pFM2, pM2, pF2, rn, out);
  } else {
    float* rn_i = (float*)d_ws;
    rownorm_zero_kernel<<<B_ROWS / 4, 256, 0, stream>>>(f, mask, rn_i, out);
    dim3 grid(B_ROWS / 128, B_ROWS / 128);
    fused_loss_kernel<<<grid, NTHREADS, 0, stream>>>(f, mask, rn_i, out);
  }
}

// Round 8
// 232.846 us; speedup vs baseline: 2.4202x; 2.4202x over previous
//
#include <hip/hip_runtime.h>
#include <hip/hip_bf16.h>

// Problem constants (fixed by reference setup_inputs)
#define B_ROWS 8192
#define D_DIM  768

// Main-kernel tile config: 128(I) x 256(J) block tile, K-step 64 (fp8),
// 512 threads = 8 waves (2 wm x 4 wn), each wave owns a 64x64 output tile
// = 2x2 frags of 32x32; MX-scaled mfma_scale_f32_32x32x64_f8f6f4 (scale=1.0).
#define BI 128
#define BJ 256
#define BK 64
#define NTHREADS 512
#define KTILES (D_DIM / BK)            // 12
#define TILE_BYTES (128 * BK)          // 8192 B per fp8 panel-tile (128 rows x 64B)
#define PANEL_BYTES ((size_t)B_ROWS * (size_t)D_DIM)   // 6291456 B (fp8)

// LDS byte offsets: F(8192) FM2(8192) M2(8192) BF(16384) BF2(16384)
#define LDS_F    0
#define LDS_FM2  8192
#define LDS_M2   16384
#define LDS_BF   24576
#define LDS_BF2  40960
#define LDSBUF_BYTES 57344             // x2 = 114688 B

// Quartet-clean swizzle key (period 32 in row): rows r and r+16 get different
// keys -> lanes {l,l+16,l+32,l+48} hit 4 distinct bank-quads (R5 fix; R7-verified
// 0 bank conflicts).
#define S2(r) (((((r) >> 1) & 3)) ^ ((((r) >> 4) & 1)))

typedef __attribute__((ext_vector_type(8))) short bf16x8;           // bf16 frag (fallback)
typedef __attribute__((ext_vector_type(8))) unsigned short u16x8;   // 16B vector store
typedef __attribute__((ext_vector_type(4))) float f32x4;            // 16x16 C/D frag
typedef __attribute__((ext_vector_type(16))) float f32x16;          // 32x32 C/D frag
typedef __attribute__((ext_vector_type(4))) int i32x4;              // 16B LDS read
typedef __attribute__((ext_vector_type(8))) int i32x8;              // 32B MX A/B frag

__device__ __forceinline__ i32x8 mk8(i32x4 lo, i32x4 hi) {
  return __builtin_shufflevector(lo, hi, 0, 1, 2, 3, 4, 5, 6, 7);
}

__device__ __forceinline__ unsigned short f2bf(float x) {
  unsigned int u = __float_as_uint(x);
  u += 0x7fffu + ((u >> 16) & 1u);
  return (unsigned short)(u >> 16);
}

// fp32 -> OCP e4m3fn, round-to-nearest-even, saturate to 448.
__device__ __forceinline__ unsigned int f2fp8(float x) {
  unsigned int u = __float_as_uint(x);
  unsigned int s = (u >> 24) & 0x80u;
  unsigned int au = u & 0x7FFFFFFFu;
  if (au < 0x3C800000u) {                  // |x| < 2^-6: fp8-subnormal region
    int k = (int)rintf(__uint_as_float(au) * 512.0f);   // multiples of 2^-9
    return s | (unsigned int)k;            // k==8 rolls into smallest normal
  }
  unsigned int m = au & 0x7FFFFFu;
  unsigned int e = au >> 23;               // >= 121
  unsigned int keep = m >> 20;
  unsigned int rest = m & 0xFFFFFu;
  keep += (rest > 0x80000u) || (rest == 0x80000u && (keep & 1u));
  unsigned int v = ((e - 120u) << 3) + keep;   // carry from keep ok
  if (v > 0x7Eu) v = 0x7Eu;                // clamp to 448
  return s | v;
}

__device__ __forceinline__ float4 f4mul(float4 a, float4 b) {
  return make_float4(a.x * b.x, a.y * b.y, a.z * b.z, a.w * b.w);
}

__device__ __forceinline__ u16x8 cvt8(float4 a, float4 b) {
  u16x8 v;
  v[0] = f2bf(a.x); v[1] = f2bf(a.y); v[2] = f2bf(a.z); v[3] = f2bf(a.w);
  v[4] = f2bf(b.x); v[5] = f2bf(b.y); v[6] = f2bf(b.z); v[7] = f2bf(b.w);
  return v;
}

__device__ __forceinline__ unsigned long long pack8(float4 a, float4 b) {
  unsigned long long u = 0;
  u |= (unsigned long long)f2fp8(a.x);
  u |= (unsigned long long)f2fp8(a.y) << 8;
  u |= (unsigned long long)f2fp8(a.z) << 16;
  u |= (unsigned long long)f2fp8(a.w) << 24;
  u |= (unsigned long long)f2fp8(b.x) << 32;
  u |= (unsigned long long)f2fp8(b.y) << 40;
  u |= (unsigned long long)f2fp8(b.z) << 48;
  u |= (unsigned long long)f2fp8(b.w) << 56;
  return u;
}

// Direct global->LDS async copy, 16B per lane (wave-uniform LDS base + lane*16).
__device__ __forceinline__ void gload16(const void* g, void* l) {
  __builtin_amdgcn_global_load_lds(
      (const __attribute__((address_space(1))) unsigned int*)(uintptr_t)g,
      (__attribute__((address_space(3))) unsigned int*)(unsigned int)(uintptr_t)l,
      16, 0, 0);
}

// Pre-pass: fp32 inputs -> four e4m3 panels, tiled panel[tr][tk][128][64B].
// k is LINEAR within the 64B row; 16B chunks XOR-swizzled c' = c ^ S2(row).
// FUSED: rn[r] += sum_d f^2 m^2 (fp32 exact; rn pre-zeroed).
// (Verified correct in R7: absmax 0.0.)
__global__ __launch_bounds__(256) void convert_kernel(
    const float* __restrict__ f, const float* __restrict__ mask,
    unsigned char* __restrict__ pF, unsigned char* __restrict__ pFM2,
    unsigned char* __restrict__ pM2, unsigned char* __restrict__ pF2,
    float* __restrict__ rn) {
  const int g = blockIdx.x * 256 + threadIdx.x;   // 8192*96 chunks of 8 elems
  const int r = g / (D_DIM / 8);
  const int chunk = g - r * (D_DIM / 8);          // 0..95
  const float* fr = f + (size_t)r * D_DIM + chunk * 8;
  const float* mr = mask + (size_t)r * D_DIM + chunk * 8;
  float4 fv0 = *(const float4*)(fr);
  float4 fv1 = *(const float4*)(fr + 4);
  float4 mv0 = *(const float4*)(mr);
  float4 mv1 = *(const float4*)(mr + 4);
  float4 m20 = f4mul(mv0, mv0), m21 = f4mul(mv1, mv1);
  float4 fm0 = f4mul(fv0, m20), fm1 = f4mul(fv1, m21);
  float4 f20 = f4mul(fv0, fv0), f21 = f4mul(fv1, fv1);

  const int tr = r >> 7, rr = r & 127;
  const int tk = chunk >> 3;                      // K-64 tile 0..11
  const int c8 = chunk & 7;                       // 8B group within 64B row
  const int c  = c8 >> 1;                         // 16B chunk 0..3
  const int h8 = c8 & 1;
  const int cs = c ^ S2(rr);                      // swizzled chunk
  const size_t off = ((size_t)((tr * KTILES + tk) * 128 + rr)) * 64 + cs * 16 + h8 * 8;
  *(unsigned long long*)(pF + off)   = pack8(fv0, fv1);
  *(unsigned long long*)(pFM2 + off) = pack8(fm0, fm1);
  *(unsigned long long*)(pM2 + off)  = pack8(m20, m21);
  *(unsigned long long*)(pF2 + off)  = pack8(f20, f21);

  float s = f20.x * m20.x + f20.y * m20.y + f20.z * m20.z + f20.w * m20.w
          + f21.x * m21.x + f21.y * m21.y + f21.z * m21.z + f21.w * m21.w;
  for (int o = 16; o > 0; o >>= 1) s += __shfl_down(s, o, 32);
  if ((threadIdx.x & 31) == 0) atomicAdd(&rn[r], s);
}

// Main kernel: fused triple-GEMM + loss, MX-fp8 32x32x64 (uniform scale 1.0),
// R3-proven 2-barrier dbuf loop. R8 changes vs R7 (spill fix ONLY — math is
// R7-verified): __launch_bounds__(512,2) lifts the 128-VGPR cap; A-frags
// STREAMED one op at a time; second chunk offset derived via ^16 (XOR swizzle
// flips chunk bit 0), so static VGPR worst case ~255 < 256.
//  accS = f_i . f_j ; accN = (f_i*m2_i) . f_j ; accD = m2_i . f_j^2
__global__ __launch_bounds__(NTHREADS, 2) void fused_loss_mx_kernel(
    const unsigned char* __restrict__ pF, const unsigned char* __restrict__ pFM2,
    const unsigned char* __restrict__ pM2, const unsigned char* __restrict__ pF2,
    const float* __restrict__ rn, float* __restrict__ out) {
  __shared__ unsigned char lds[2 * LDSBUF_BYTES];
  __shared__ float red[8];

  const int t    = threadIdx.x;
  const int lane = t & 63;
  const int wv   = t >> 6;        // wave id 0..7
  const int wm   = wv >> 2;       // 0..1  (row group of 64)
  const int wn   = wv & 3;        // 0..3  (col group of 64)
  const int rl   = lane & 31;     // fragment row within 32-row block
  const int u    = lane >> 5;     // k-half selector (0/1): k = u*32..u*32+31

  const int trA = blockIdx.y;     // i0 = trA*128
  const int trB = blockIdx.x;     // j0 = trB*256 -> panel row-tiles 2trB, 2trB+1
  const int te  = t * 16;         // staging byte offset (16B per thread)

  const size_t baseA  = (size_t)(trA * KTILES) * TILE_BYTES;
  const size_t baseB0 = (size_t)((2 * trB) * KTILES) * TILE_BYTES;
  const size_t baseB1 = (size_t)((2 * trB + 1) * KTILES) * TILE_BYTES;

  // Swizzled ds_read byte offsets for chunk 2u; chunk 2u+1 is (off ^ 16).
  int offA[2], offB[2];
#pragma unroll
  for (int mt = 0; mt < 2; ++mt) {
    const int r = wm * 64 + mt * 32 + rl;             // 0..127
    offA[mt] = r * 64 + (((2 * u) ^ S2(r)) << 4);
  }
#pragma unroll
  for (int nt = 0; nt < 2; ++nt) {
    const int rB = wn * 64 + nt * 32 + rl;            // 0..255
    const int rt = rB >> 7, rr = rB & 127;
    offB[nt] = rt * TILE_BYTES + rr * 64 + (((2 * u) ^ S2(rr)) << 4);
  }

  f32x16 accS[2][2], accN[2][2], accD[2][2];
#pragma unroll
  for (int mt = 0; mt < 2; ++mt)
#pragma unroll
    for (int nt = 0; nt < 2; ++nt)
#pragma unroll
      for (int r = 0; r < 16; ++r) {
        accS[mt][nt][r] = 0.f;
        accN[mt][nt][r] = 0.f;
        accD[mt][nt][r] = 0.f;
      }

#define STAGE(b, tk)                                                          \
  do {                                                                        \
    const size_t _tA  = baseA  + (size_t)(tk) * TILE_BYTES + te;              \
    const size_t _tB0 = baseB0 + (size_t)(tk) * TILE_BYTES + te;              \
    const size_t _tB1 = baseB1 + (size_t)(tk) * TILE_BYTES + te;              \
    gload16(pF   + _tA,  (b) + LDS_F   + te);                                 \
    gload16(pFM2 + _tA,  (b) + LDS_FM2 + te);                                 \
    gload16(pM2  + _tA,  (b) + LDS_M2  + te);                                 \
    gload16(pF   + _tB0, (b) + LDS_BF  + te);                                 \
    gload16(pF   + _tB1, (b) + LDS_BF  + TILE_BYTES + te);                    \
    gload16(pF2  + _tB0, (b) + LDS_BF2 + te);                                 \
    gload16(pF2  + _tB1, (b) + LDS_BF2 + TILE_BYTES + te);                    \
  } while (0)

  unsigned char* const buf0 = lds;
  unsigned char* const buf1 = lds + LDSBUF_BYTES;

  STAGE(buf0, 0);
  asm volatile("s_waitcnt vmcnt(0)" ::: "memory");
  __syncthreads();

  int cur = 0;
  for (int tk = 0; tk < KTILES; ++tk) {
    unsigned char* const cb = cur ? buf1 : buf0;
    unsigned char* const nb = cur ? buf0 : buf1;
    if (tk + 1 < KTILES) STAGE(nb, tk + 1);   // prefetch issued BEFORE compute

    // Hold the 4 B-frags (32 VGPR); stream A-frags one op at a time.
    i32x8 bF[2], bF2[2];
#pragma unroll
    for (int nt = 0; nt < 2; ++nt) {
      bF[nt]  = mk8(*(const i32x4*)(cb + LDS_BF  + offB[nt]),
                    *(const i32x4*)(cb + LDS_BF  + (offB[nt] ^ 16)));
      bF2[nt] = mk8(*(const i32x4*)(cb + LDS_BF2 + offB[nt]),
                    *(const i32x4*)(cb + LDS_BF2 + (offB[nt] ^ 16)));
    }
#pragma unroll
    for (int mt = 0; mt < 2; ++mt) {
      {
        i32x8 aF = mk8(*(const i32x4*)(cb + LDS_F + offA[mt]),
                       *(const i32x4*)(cb + LDS_F + (offA[mt] ^ 16)));
        accS[mt][0] = __builtin_amdgcn_mfma_scale_f32_32x32x64_f8f6f4(
            aF, bF[0], accS[mt][0], 0, 0, 0, 127, 0, 127);
        accS[mt][1] = __builtin_amdgcn_mfma_scale_f32_32x32x64_f8f6f4(
            aF, bF[1], accS[mt][1], 0, 0, 0, 127, 0, 127);
      }
      {
        i32x8 aN = mk8(*(const i32x4*)(cb + LDS_FM2 + offA[mt]),
                       *(const i32x4*)(cb + LDS_FM2 + (offA[mt] ^ 16)));
        accN[mt][0] = __builtin_amdgcn_mfma_scale_f32_32x32x64_f8f6f4(
            aN, bF[0], accN[mt][0], 0, 0, 0, 127, 0, 127);
        accN[mt][1] = __builtin_amdgcn_mfma_scale_f32_32x32x64_f8f6f4(
            aN, bF[1], accN[mt][1], 0, 0, 0, 127, 0, 127);
      }
      {
        i32x8 aD = mk8(*(const i32x4*)(cb + LDS_M2 + offA[mt]),
                       *(const i32x4*)(cb + LDS_M2 + (offA[mt] ^ 16)));
        accD[mt][0] = __builtin_amdgcn_mfma_scale_f32_32x32x64_f8f6f4(
            aD, bF2[0], accD[mt][0], 0, 0, 0, 127, 0, 127);
        accD[mt][1] = __builtin_amdgcn_mfma_scale_f32_32x32x64_f8f6f4(
            aD, bF2[1], accD[mt][1], 0, 0, 0, 127, 0, 127);
      }
    }
    asm volatile("s_waitcnt vmcnt(0)" ::: "memory");
    __syncthreads();
    cur ^= 1;
  }
#undef STAGE

  // ---- epilogue: pointwise loss + off-diagonal masked reduction ----
  // 32x32 C/D layout (m74/m101-verified; R7-passed): col = lane&31,
  // row = (reg&3) + 8*(reg>>2) + 4*(lane>>5)
  float sum = 0.f;
  const int i0 = trA * BI;
  const int j0 = trB * BJ;
  const int rhi = u * 4;
#pragma unroll
  for (int mt = 0; mt < 2; ++mt) {
#pragma unroll
    for (int r = 0; r < 16; ++r) {
      const int row = (r & 3) + 8 * (r >> 2) + rhi;
      const int gi = i0 + wm * 64 + mt * 32 + row;
      // rn holds sum_d f^2 m^2 ; 1/max(sqrt(s),1e-12) == rsqrt(max(s,1e-24))
      const float rni = rsqrtf(fmaxf(rn[gi], 1e-24f));
#pragma unroll
      for (int nt = 0; nt < 2; ++nt) {
        const int gj = j0 + wn * 64 + nt * 32 + rl;
        const float sfull = accS[mt][nt][r];
        const float num   = accN[mt][nt][r];
        const float nd    = accD[mt][nt][r];
        const float rnij  = rsqrtf(fmaxf(nd, 1e-24f));
        const float sim   = num * rni * rnij;
        const float d     = fabsf(sfull - sim);
        if (gi != gj) sum += d;
      }
    }
  }
  for (int off = 32; off > 0; off >>= 1) sum += __shfl_down(sum, off);
  if (lane == 0) red[wv] = sum;
  __syncthreads();
  if (t == 0) {
    float bs = 0.f;
    for (int w = 0; w < 8; ++w) bs += red[w];
    const float scale = 1.0f / (8192.0f * 8191.0f);
    atomicAdd(out, bs * scale);
  }
}

// ---------------- Fallback path (ws too small): round-1 kernels ---------------
__global__ __launch_bounds__(256) void rownorm_zero_kernel(
    const float* __restrict__ f, const float* __restrict__ mask,
    float* __restrict__ rn_i, float* __restrict__ out) {
  if (blockIdx.x == 0 && threadIdx.x == 0) out[0] = 0.0f;
  const int wv = threadIdx.x >> 6;
  const int lane = threadIdx.x & 63;
  const int row = blockIdx.x * 4 + wv;
  const float* fr = f + (size_t)row * D_DIM;
  const float* mr = mask + (size_t)row * D_DIM;
  float s = 0.f;
  for (int d = lane; d < D_DIM; d += 64) {
    float v = fr[d] * mr[d];
    s += v * v;
  }
  for (int off = 32; off > 0; off >>= 1) s += __shfl_down(s, off);
  if (lane == 0) rn_i[row] = 1.0f / fmaxf(sqrtf(s), 1e-12f);
}

__global__ __launch_bounds__(NTHREADS, 2) void fused_loss_kernel(
    const float* __restrict__ f, const float* __restrict__ mask,
    const float* __restrict__ rn_i, float* __restrict__ out) {
  __shared__ unsigned short sF[128][32];
  __shared__ unsigned short sFM2[128][32];
  __shared__ unsigned short sM2[128][32];
  __shared__ unsigned short sBF[128][32];
  __shared__ unsigned short sBF2[128][32];
  __shared__ float red[8];

  const int t    = threadIdx.x;
  const int lane = t & 63;
  const int wv   = t >> 6;
  const int wm   = wv >> 2;
  const int wn   = wv & 3;
  const int frg  = lane & 15;
  const int ko   = (lane >> 4) * 8;

  const int i0 = blockIdx.y * 128;
  const int j0 = blockIdx.x * 128;
  const int ar = t >> 2;
  const int ac = (t & 3) * 8;

  f32x4 accS[4][2], accN[4][2], accD[4][2];
  for (int m = 0; m < 4; ++m)
    for (int n = 0; n < 2; ++n) {
      accS[m][n] = {0.f, 0.f, 0.f, 0.f};
      accN[m][n] = {0.f, 0.f, 0.f, 0.f};
      accD[m][n] = {0.f, 0.f, 0.f, 0.f};
    }

  const float* fA = f    + (size_t)(i0 + ar) * D_DIM + ac;
  const float* mA = mask + (size_t)(i0 + ar) * D_DIM + ac;
  const float* fB = f    + (size_t)(j0 + ar) * D_DIM + ac;

  for (int k0 = 0; k0 < D_DIM; k0 += 32) {
    __syncthreads();
    float4 fa0 = *(const float4*)(fA + k0);
    float4 fa1 = *(const float4*)(fA + k0 + 4);
    float4 ma0 = *(const float4*)(mA + k0);
    float4 ma1 = *(const float4*)(mA + k0 + 4);
    float4 fb0 = *(const float4*)(fB + k0);
    float4 fb1 = *(const float4*)(fB + k0 + 4);
    float4 m20 = f4mul(ma0, ma0), m21 = f4mul(ma1, ma1);
    float4 fm0 = f4mul(fa0, m20), fm1 = f4mul(fa1, m21);
    float4 f20 = f4mul(fb0, fb0), f21 = f4mul(fb1, fb1);
    *(u16x8*)&sF[ar][ac]   = cvt8(fa0, fa1);
    *(u16x8*)&sFM2[ar][ac] = cvt8(fm0, fm1);
    *(u16x8*)&sM2[ar][ac]  = cvt8(m20, m21);
    *(u16x8*)&sBF[ar][ac]  = cvt8(fb0, fb1);
    *(u16x8*)&sBF2[ar][ac] = cvt8(f20, f21);
    __syncthreads();
    bf16x8 bF[2], bF2[2];
    for (int n = 0; n < 2; ++n) {
      bF[n]  = *(const bf16x8*)&sBF [wn * 32 + n * 16 + frg][ko];
      bF2[n] = *(const bf16x8*)&sBF2[wn * 32 + n * 16 + frg][ko];
    }
#pragma unroll
    for (int m = 0; m < 4; ++m) {
      bf16x8 aF = *(const bf16x8*)&sF  [wm * 64 + m * 16 + frg][ko];
      bf16x8 aN = *(const bf16x8*)&sFM2[wm * 64 + m * 16 + frg][ko];
      bf16x8 aD = *(const bf16x8*)&sM2 [wm * 64 + m * 16 + frg][ko];
#pragma unroll
      for (int n = 0; n < 2; ++n) {
        accS[m][n] = __builtin_amdgcn_mfma_f32_16x16x32_bf16(aF, bF[n],  accS[m][n], 0, 0, 0);
        accN[m][n] = __builtin_amdgcn_mfma_f32_16x16x32_bf16(aN, bF[n],  accN[m][n], 0, 0, 0);
        accD[m][n] = __builtin_amdgcn_mfma_f32_16x16x32_bf16(aD, bF2[n], accD[m][n], 0, 0, 0);
      }
    }
  }

  float sum = 0.f;
  const int r4 = (lane >> 4) * 4;
  const int cc = lane & 15;
#pragma unroll
  for (int m = 0; m < 4; ++m) {
    const int gi_base = i0 + wm * 64 + m * 16 + r4;
#pragma unroll
    for (int jj = 0; jj < 4; ++jj) {
      const int gi = gi_base + jj;
      const float rni = rn_i[gi];
#pragma unroll
      for (int n = 0; n < 2; ++n) {
        const int gj = j0 + wn * 32 + n * 16 + cc;
        const float sfull = accS[m][n][jj];
        const float num   = accN[m][n][jj];
        const float nd    = accD[m][n][jj];
        const float rnij  = rsqrtf(fmaxf(nd, 1e-24f));
        const float sim   = num * rni * rnij;
        const float d     = fabsf(sfull - sim);
        if (gi != gj) sum += d;
      }
    }
  }
  for (int off = 32; off > 0; off >>= 1) sum += __shfl_down(sum, off);
  if (lane == 0) red[wv] = sum;
  __syncthreads();
  if (t == 0) {
    float bs = 0.f;
    for (int w = 0; w < 8; ++w) bs += red[w];
    const float scale = 1.0f / (8192.0f * 8191.0f);
    atomicAdd(out, bs * scale);
  }
}

extern "C" void kernel_launch(void* const* d_in, const int* in_sizes, int n_in,
                              void* d_out, int out_size, void* d_ws, size_t ws_size,
                              hipStream_t stream) {
  const float* f    = (const float*)d_in[0];   // full_emb [8192,768] fp32
  const float* mask = (const float*)d_in[1];   // query_mask [8192,768] fp32
  float* out = (float*)d_out;                  // scalar loss

  const size_t need = 4 * PANEL_BYTES + (size_t)B_ROWS * sizeof(float);
  if (ws_size >= need) {
    unsigned char* pF   = (unsigned char*)d_ws;
    unsigned char* pFM2 = pF + PANEL_BYTES;
    unsigned char* pM2  = pFM2 + PANEL_BYTES;
    unsigned char* pF2  = pM2 + PANEL_BYTES;
    float* rn = (float*)(pF2 + PANEL_BYTES);
    hipMemsetAsync(rn, 0, B_ROWS * sizeof(float), stream);
    hipMemsetAsync(out, 0, sizeof(float), stream);
    convert_kernel<<<(B_ROWS * (D_DIM / 8)) / 256, 256, 0, stream>>>(
        f, mask, pF, pFM2, pM2, pF2, rn);
    dim3 grid(B_ROWS / BJ, B_ROWS / BI);   // 32 x 64
    fused_loss_mx_kernel<<<grid, NTHREADS, 0, stream>>>(pF, pFM2, pM2, pF2, rn, out);
  } else {
    float* rn_i = (float*)d_ws;
    rownorm_zero_kernel<<<B_ROWS / 4, 256, 0, stream>>>(f, mask, rn_i, out);
    dim3 grid(B_ROWS / 128, B_ROWS / 128);
    fused_loss_kernel<<<grid, NTHREADS, 0, stream>>>(f, mask, rn_i, out);
  }
}

// Round 9
// 219.768 us; speedup vs baseline: 2.5642x; 1.0595x over previous
//
#include <hip/hip_runtime.h>
#include <hip/hip_bf16.h>

// Problem constants (fixed by reference setup_inputs)
#define B_ROWS 8192
#define D_DIM  768

// Main-kernel tile config: 128(I) x 256(J) block tile, K-step 64 (fp8),
// 512 threads = 8 waves (2 wm x 4 wn), each wave owns a 64x64 output tile
// = 2x2 frags of 32x32; MX-scaled mfma_scale_f32_32x32x64_f8f6f4 (scale=1.0).
#define BI 128
#define BJ 256
#define BK 64
#define NTHREADS 512
#define KTILES (D_DIM / BK)            // 12
#define TILE_BYTES (128 * BK)          // 8192 B per fp8 panel-tile (128 rows x 64B)
#define PANEL_BYTES ((size_t)B_ROWS * (size_t)D_DIM)   // 6291456 B (fp8)

// LDS byte offsets: F(8192) FM2(8192) M2(8192) BF(16384) BF2(16384)
#define LDS_F    0
#define LDS_FM2  8192
#define LDS_M2   16384
#define LDS_BF   24576
#define LDS_BF2  40960
#define LDSBUF_BYTES 57344             // x2 = 114688 B

// Quartet-clean swizzle key (period 32 in row): rows r and r+16 get different
// keys -> lanes {l,l+16,l+32,l+48} hit 4 distinct bank-quads (R7/R8-verified
// 0 bank conflicts).
#define S2(r) (((((r) >> 1) & 3)) ^ ((((r) >> 4) & 1)))

typedef __attribute__((ext_vector_type(8))) short bf16x8;           // bf16 frag (fallback)
typedef __attribute__((ext_vector_type(8))) unsigned short u16x8;   // 16B vector store
typedef __attribute__((ext_vector_type(4))) float f32x4;            // 16x16 C/D frag
typedef __attribute__((ext_vector_type(16))) float f32x16;          // 32x32 C/D frag
typedef __attribute__((ext_vector_type(4))) int i32x4;              // 16B LDS read
typedef __attribute__((ext_vector_type(8))) int i32x8;              // 32B MX A/B frag

__device__ __forceinline__ i32x8 mk8(i32x4 lo, i32x4 hi) {
  return __builtin_shufflevector(lo, hi, 0, 1, 2, 3, 4, 5, 6, 7);
}

__device__ __forceinline__ unsigned short f2bf(float x) {
  unsigned int u = __float_as_uint(x);
  u += 0x7fffu + ((u >> 16) & 1u);
  return (unsigned short)(u >> 16);
}

// fp32 -> OCP e4m3fn, round-to-nearest-even, saturate to 448. (software path)
__device__ __forceinline__ unsigned int f2fp8(float x) {
  unsigned int u = __float_as_uint(x);
  unsigned int s = (u >> 24) & 0x80u;
  unsigned int au = u & 0x7FFFFFFFu;
  if (au < 0x3C800000u) {                  // |x| < 2^-6: fp8-subnormal region
    int k = (int)rintf(__uint_as_float(au) * 512.0f);   // multiples of 2^-9
    return s | (unsigned int)k;            // k==8 rolls into smallest normal
  }
  unsigned int m = au & 0x7FFFFFu;
  unsigned int e = au >> 23;               // >= 121
  unsigned int keep = m >> 20;
  unsigned int rest = m & 0xFFFFFu;
  keep += (rest > 0x80000u) || (rest == 0x80000u && (keep & 1u));
  unsigned int v = ((e - 120u) << 3) + keep;   // carry from keep ok
  if (v > 0x7Eu) v = 0x7Eu;                // clamp to 448
  return s | v;
}

__device__ __forceinline__ float4 f4mul(float4 a, float4 b) {
  return make_float4(a.x * b.x, a.y * b.y, a.z * b.z, a.w * b.w);
}

__device__ __forceinline__ u16x8 cvt8(float4 a, float4 b) {
  u16x8 v;
  v[0] = f2bf(a.x); v[1] = f2bf(a.y); v[2] = f2bf(a.z); v[3] = f2bf(a.w);
  v[4] = f2bf(b.x); v[5] = f2bf(b.y); v[6] = f2bf(b.z); v[7] = f2bf(b.w);
  return v;
}

// pack 8 floats -> 8 e4m3 bytes. HW cvt_pk path when available (4 instrs);
// identical-packer-on-both-operands means any rounding nuance is consistent.
__device__ __forceinline__ unsigned long long pack8(float4 a, float4 b) {
#if __has_builtin(__builtin_amdgcn_cvt_pk_fp8_f32)
  unsigned int lo = (unsigned int)__builtin_amdgcn_cvt_pk_fp8_f32(a.x, a.y, 0, false);
  lo = (unsigned int)__builtin_amdgcn_cvt_pk_fp8_f32(a.z, a.w, (int)lo, true);
  unsigned int hi = (unsigned int)__builtin_amdgcn_cvt_pk_fp8_f32(b.x, b.y, 0, false);
  hi = (unsigned int)__builtin_amdgcn_cvt_pk_fp8_f32(b.z, b.w, (int)hi, true);
  return (unsigned long long)lo | ((unsigned long long)hi << 32);
#else
  unsigned long long u = 0;
  u |= (unsigned long long)f2fp8(a.x);
  u |= (unsigned long long)f2fp8(a.y) << 8;
  u |= (unsigned long long)f2fp8(a.z) << 16;
  u |= (unsigned long long)f2fp8(a.w) << 24;
  u |= (unsigned long long)f2fp8(b.x) << 32;
  u |= (unsigned long long)f2fp8(b.y) << 40;
  u |= (unsigned long long)f2fp8(b.z) << 48;
  u |= (unsigned long long)f2fp8(b.w) << 56;
  return u;
#endif
}

// Direct global->LDS async copy, 16B per lane (wave-uniform LDS base + lane*16).
__device__ __forceinline__ void gload16(const void* g, void* l) {
  __builtin_amdgcn_global_load_lds(
      (const __attribute__((address_space(1))) unsigned int*)(uintptr_t)g,
      (__attribute__((address_space(3))) unsigned int*)(unsigned int)(uintptr_t)l,
      16, 0, 0);
}

// Pre-pass: fp32 inputs -> four e4m3 panels, tiled panel[tr][tk][128][64B].
// k is LINEAR within the 64B row; 16B chunks XOR-swizzled c' = c ^ S2(row).
// FUSED: rn[r] += sum_d f^2 m^2 (fp32 exact; rn pre-zeroed).
__global__ __launch_bounds__(256) void convert_kernel(
    const float* __restrict__ f, const float* __restrict__ mask,
    unsigned char* __restrict__ pF, unsigned char* __restrict__ pFM2,
    unsigned char* __restrict__ pM2, unsigned char* __restrict__ pF2,
    float* __restrict__ rn) {
  const int g = blockIdx.x * 256 + threadIdx.x;   // 8192*96 chunks of 8 elems
  const int r = g / (D_DIM / 8);
  const int chunk = g - r * (D_DIM / 8);          // 0..95
  const float* fr = f + (size_t)r * D_DIM + chunk * 8;
  const float* mr = mask + (size_t)r * D_DIM + chunk * 8;
  float4 fv0 = *(const float4*)(fr);
  float4 fv1 = *(const float4*)(fr + 4);
  float4 mv0 = *(const float4*)(mr);
  float4 mv1 = *(const float4*)(mr + 4);
  float4 m20 = f4mul(mv0, mv0), m21 = f4mul(mv1, mv1);
  float4 fm0 = f4mul(fv0, m20), fm1 = f4mul(fv1, m21);
  float4 f20 = f4mul(fv0, fv0), f21 = f4mul(fv1, fv1);

  const int tr = r >> 7, rr = r & 127;
  const int tk = chunk >> 3;                      // K-64 tile 0..11
  const int c8 = chunk & 7;                       // 8B group within 64B row
  const int c  = c8 >> 1;                         // 16B chunk 0..3
  const int h8 = c8 & 1;
  const int cs = c ^ S2(rr);                      // swizzled chunk
  const size_t off = ((size_t)((tr * KTILES + tk) * 128 + rr)) * 64 + cs * 16 + h8 * 8;
  *(unsigned long long*)(pF + off)   = pack8(fv0, fv1);
  *(unsigned long long*)(pFM2 + off) = pack8(fm0, fm1);
  *(unsigned long long*)(pM2 + off)  = pack8(m20, m21);
  *(unsigned long long*)(pF2 + off)  = pack8(f20, f21);

  float s = f20.x * m20.x + f20.y * m20.y + f20.z * m20.z + f20.w * m20.w
          + f21.x * m21.x + f21.y * m21.y + f21.z * m21.z + f21.w * m21.w;
  for (int o = 16; o > 0; o >>= 1) s += __shfl_down(s, o, 32);
  if ((threadIdx.x & 31) == 0) atomicAdd(&rn[r], s);
}

// Main kernel: fused triple-GEMM + loss, MX-fp8 32x32x64 (uniform scale 1.0),
// R3-proven 2-barrier dbuf loop; R8-verified math/register schedule.
// R9 change: 1D grid + XCD-chunked (trA,trB) mapping — each XCD owns an
// 8-wide trA slab (A slices stay L2-resident) and walks trB so 8 consecutive
// blocks share each B tile (B served from L2, not L3).
//  accS = f_i . f_j ; accN = (f_i*m2_i) . f_j ; accD = m2_i . f_j^2
__global__ __launch_bounds__(NTHREADS, 2) void fused_loss_mx_kernel(
    const unsigned char* __restrict__ pF, const unsigned char* __restrict__ pFM2,
    const unsigned char* __restrict__ pM2, const unsigned char* __restrict__ pF2,
    const float* __restrict__ rn, float* __restrict__ out) {
  __shared__ unsigned char lds[2 * LDSBUF_BYTES];
  __shared__ float red[8];

  const int t    = threadIdx.x;
  const int lane = t & 63;
  const int wv   = t >> 6;        // wave id 0..7
  const int wm   = wv >> 2;       // 0..1  (row group of 64)
  const int wn   = wv & 3;        // 0..3  (col group of 64)
  const int rl   = lane & 31;     // fragment row within 32-row block
  const int u    = lane >> 5;     // k-half selector (0/1): k = u*32..u*32+31

  // XCD-chunked block mapping (bijective: 2048 ids -> 64 trA x 32 trB).
  const int id  = blockIdx.x;
  const int xcd = id & 7;
  const int c   = id >> 3;        // 0..255 per XCD
  const int trB = c >> 3;         // 0..31 (8 consecutive blocks share trB)
  const int trA = xcd * 8 + (c & 7);   // 0..63 (8-wide slab per XCD)

  const int te  = t * 16;         // staging byte offset (16B per thread)

  const size_t baseA  = (size_t)(trA * KTILES) * TILE_BYTES;
  const size_t baseB0 = (size_t)((2 * trB) * KTILES) * TILE_BYTES;
  const size_t baseB1 = (size_t)((2 * trB + 1) * KTILES) * TILE_BYTES;

  // Swizzled ds_read byte offsets for chunk 2u; chunk 2u+1 is (off ^ 16).
  int offA[2], offB[2];
#pragma unroll
  for (int mt = 0; mt < 2; ++mt) {
    const int r = wm * 64 + mt * 32 + rl;             // 0..127
    offA[mt] = r * 64 + (((2 * u) ^ S2(r)) << 4);
  }
#pragma unroll
  for (int nt = 0; nt < 2; ++nt) {
    const int rB = wn * 64 + nt * 32 + rl;            // 0..255
    const int rt = rB >> 7, rr = rB & 127;
    offB[nt] = rt * TILE_BYTES + rr * 64 + (((2 * u) ^ S2(rr)) << 4);
  }

  f32x16 accS[2][2], accN[2][2], accD[2][2];
#pragma unroll
  for (int mt = 0; mt < 2; ++mt)
#pragma unroll
    for (int nt = 0; nt < 2; ++nt)
#pragma unroll
      for (int r = 0; r < 16; ++r) {
        accS[mt][nt][r] = 0.f;
        accN[mt][nt][r] = 0.f;
        accD[mt][nt][r] = 0.f;
      }

#define STAGE(b, tk)                                                          \
  do {                                                                        \
    const size_t _tA  = baseA  + (size_t)(tk) * TILE_BYTES + te;              \
    const size_t _tB0 = baseB0 + (size_t)(tk) * TILE_BYTES + te;              \
    const size_t _tB1 = baseB1 + (size_t)(tk) * TILE_BYTES + te;              \
    gload16(pF   + _tA,  (b) + LDS_F   + te);                                 \
    gload16(pFM2 + _tA,  (b) + LDS_FM2 + te);                                 \
    gload16(pM2  + _tA,  (b) + LDS_M2  + te);                                 \
    gload16(pF   + _tB0, (b) + LDS_BF  + te);                                 \
    gload16(pF   + _tB1, (b) + LDS_BF  + TILE_BYTES + te);                    \
    gload16(pF2  + _tB0, (b) + LDS_BF2 + te);                                 \
    gload16(pF2  + _tB1, (b) + LDS_BF2 + TILE_BYTES + te);                    \
  } while (0)

  unsigned char* const buf0 = lds;
  unsigned char* const buf1 = lds + LDSBUF_BYTES;

  STAGE(buf0, 0);
  asm volatile("s_waitcnt vmcnt(0)" ::: "memory");
  __syncthreads();

  int cur = 0;
  for (int tk = 0; tk < KTILES; ++tk) {
    unsigned char* const cb = cur ? buf1 : buf0;
    unsigned char* const nb = cur ? buf0 : buf1;
    if (tk + 1 < KTILES) STAGE(nb, tk + 1);   // prefetch issued BEFORE compute

    // Hold the 4 B-frags (32 VGPR); stream A-frags one op at a time.
    i32x8 bF[2], bF2[2];
#pragma unroll
    for (int nt = 0; nt < 2; ++nt) {
      bF[nt]  = mk8(*(const i32x4*)(cb + LDS_BF  + offB[nt]),
                    *(const i32x4*)(cb + LDS_BF  + (offB[nt] ^ 16)));
      bF2[nt] = mk8(*(const i32x4*)(cb + LDS_BF2 + offB[nt]),
                    *(const i32x4*)(cb + LDS_BF2 + (offB[nt] ^ 16)));
    }
#pragma unroll
    for (int mt = 0; mt < 2; ++mt) {
      {
        i32x8 aF = mk8(*(const i32x4*)(cb + LDS_F + offA[mt]),
                       *(const i32x4*)(cb + LDS_F + (offA[mt] ^ 16)));
        accS[mt][0] = __builtin_amdgcn_mfma_scale_f32_32x32x64_f8f6f4(
            aF, bF[0], accS[mt][0], 0, 0, 0, 127, 0, 127);
        accS[mt][1] = __builtin_amdgcn_mfma_scale_f32_32x32x64_f8f6f4(
            aF, bF[1], accS[mt][1], 0, 0, 0, 127, 0, 127);
      }
      {
        i32x8 aN = mk8(*(const i32x4*)(cb + LDS_FM2 + offA[mt]),
                       *(const i32x4*)(cb + LDS_FM2 + (offA[mt] ^ 16)));
        accN[mt][0] = __builtin_amdgcn_mfma_scale_f32_32x32x64_f8f6f4(
            aN, bF[0], accN[mt][0], 0, 0, 0, 127, 0, 127);
        accN[mt][1] = __builtin_amdgcn_mfma_scale_f32_32x32x64_f8f6f4(
            aN, bF[1], accN[mt][1], 0, 0, 0, 127, 0, 127);
      }
      {
        i32x8 aD = mk8(*(const i32x4*)(cb + LDS_M2 + offA[mt]),
                       *(const i32x4*)(cb + LDS_M2 + (offA[mt] ^ 16)));
        accD[mt][0] = __builtin_amdgcn_mfma_scale_f32_32x32x64_f8f6f4(
            aD, bF2[0], accD[mt][0], 0, 0, 0, 127, 0, 127);
        accD[mt][1] = __builtin_amdgcn_mfma_scale_f32_32x32x64_f8f6f4(
            aD, bF2[1], accD[mt][1], 0, 0, 0, 127, 0, 127);
      }
    }
    asm volatile("s_waitcnt vmcnt(0)" ::: "memory");
    __syncthreads();
    cur ^= 1;
  }
#undef STAGE

  // ---- epilogue: pointwise loss + off-diagonal masked reduction ----
  // 32x32 C/D layout (m74/m101-verified; R7/R8-passed): col = lane&31,
  // row = (reg&3) + 8*(reg>>2) + 4*(lane>>5)
  float sum = 0.f;
  const int i0 = trA * BI;
  const int j0 = trB * BJ;
  const int rhi = u * 4;
#pragma unroll
  for (int mt = 0; mt < 2; ++mt) {
#pragma unroll
    for (int r = 0; r < 16; ++r) {
      const int row = (r & 3) + 8 * (r >> 2) + rhi;
      const int gi = i0 + wm * 64 + mt * 32 + row;
      // rn holds sum_d f^2 m^2 ; 1/max(sqrt(s),1e-12) == rsqrt(max(s,1e-24))
      const float rni = rsqrtf(fmaxf(rn[gi], 1e-24f));
#pragma unroll
      for (int nt = 0; nt < 2; ++nt) {
        const int gj = j0 + wn * 64 + nt * 32 + rl;
        const float sfull = accS[mt][nt][r];
        const float num   = accN[mt][nt][r];
        const float nd    = accD[mt][nt][r];
        const float rnij  = rsqrtf(fmaxf(nd, 1e-24f));
        const float sim   = num * rni * rnij;
        const float d     = fabsf(sfull - sim);
        if (gi != gj) sum += d;
      }
    }
  }
  for (int off = 32; off > 0; off >>= 1) sum += __shfl_down(sum, off);
  if (lane == 0) red[wv] = sum;
  __syncthreads();
  if (t == 0) {
    float bs = 0.f;
    for (int w = 0; w < 8; ++w) bs += red[w];
    const float scale = 1.0f / (8192.0f * 8191.0f);
    atomicAdd(out, bs * scale);
  }
}

// ---------------- Fallback path (ws too small): round-1 kernels ---------------
__global__ __launch_bounds__(256) void rownorm_zero_kernel(
    const float* __restrict__ f, const float* __restrict__ mask,
    float* __restrict__ rn_i, float* __restrict__ out) {
  if (blockIdx.x == 0 && threadIdx.x == 0) out[0] = 0.0f;
  const int wv = threadIdx.x >> 6;
  const int lane = threadIdx.x & 63;
  const int row = blockIdx.x * 4 + wv;
  const float* fr = f + (size_t)row * D_DIM;
  const float* mr = mask + (size_t)row * D_DIM;
  float s = 0.f;
  for (int d = lane; d < D_DIM; d += 64) {
    float v = fr[d] * mr[d];
    s += v * v;
  }
  for (int off = 32; off > 0; off >>= 1) s += __shfl_down(s, off);
  if (lane == 0) rn_i[row] = 1.0f / fmaxf(sqrtf(s), 1e-12f);
}

__global__ __launch_bounds__(NTHREADS, 2) void fused_loss_kernel(
    const float* __restrict__ f, const float* __restrict__ mask,
    const float* __restrict__ rn_i, float* __restrict__ out) {
  __shared__ unsigned short sF[128][32];
  __shared__ unsigned short sFM2[128][32];
  __shared__ unsigned short sM2[128][32];
  __shared__ unsigned short sBF[128][32];
  __shared__ unsigned short sBF2[128][32];
  __shared__ float red[8];

  const int t    = threadIdx.x;
  const int lane = t & 63;
  const int wv   = t >> 6;
  const int wm   = wv >> 2;
  const int wn   = wv & 3;
  const int frg  = lane & 15;
  const int ko   = (lane >> 4) * 8;

  const int i0 = blockIdx.y * 128;
  const int j0 = blockIdx.x * 128;
  const int ar = t >> 2;
  const int ac = (t & 3) * 8;

  f32x4 accS[4][2], accN[4][2], accD[4][2];
  for (int m = 0; m < 4; ++m)
    for (int n = 0; n < 2; ++n) {
      accS[m][n] = {0.f, 0.f, 0.f, 0.f};
      accN[m][n] = {0.f, 0.f, 0.f, 0.f};
      accD[m][n] = {0.f, 0.f, 0.f, 0.f};
    }

  const float* fA = f    + (size_t)(i0 + ar) * D_DIM + ac;
  const float* mA = mask + (size_t)(i0 + ar) * D_DIM + ac;
  const float* fB = f    + (size_t)(j0 + ar) * D_DIM + ac;

  for (int k0 = 0; k0 < D_DIM; k0 += 32) {
    __syncthreads();
    float4 fa0 = *(const float4*)(fA + k0);
    float4 fa1 = *(const float4*)(fA + k0 + 4);
    float4 ma0 = *(const float4*)(mA + k0);
    float4 ma1 = *(const float4*)(mA + k0 + 4);
    float4 fb0 = *(const float4*)(fB + k0);
    float4 fb1 = *(const float4*)(fB + k0 + 4);
    float4 m20 = f4mul(ma0, ma0), m21 = f4mul(ma1, ma1);
    float4 fm0 = f4mul(fa0, m20), fm1 = f4mul(fa1, m21);
    float4 f20 = f4mul(fb0, fb0), f21 = f4mul(fb1, fb1);
    *(u16x8*)&sF[ar][ac]   = cvt8(fa0, fa1);
    *(u16x8*)&sFM2[ar][ac] = cvt8(fm0, fm1);
    *(u16x8*)&sM2[ar][ac]  = cvt8(m20, m21);
    *(u16x8*)&sBF[ar][ac]  = cvt8(fb0, fb1);
    *(u16x8*)&sBF2[ar][ac] = cvt8(f20, f21);
    __syncthreads();
    bf16x8 bF[2], bF2[2];
    for (int n = 0; n < 2; ++n) {
      bF[n]  = *(const bf16x8*)&sBF [wn * 32 + n * 16 + frg][ko];
      bF2[n] = *(const bf16x8*)&sBF2[wn * 32 + n * 16 + frg][ko];
    }
#pragma unroll
    for (int m = 0; m < 4; ++m) {
      bf16x8 aF = *(const bf16x8*)&sF  [wm * 64 + m * 16 + frg][ko];
      bf16x8 aN = *(const bf16x8*)&sFM2[wm * 64 + m * 16 + frg][ko];
      bf16x8 aD = *(const bf16x8*)&sM2 [wm * 64 + m * 16 + frg][ko];
#pragma unroll
      for (int n = 0; n < 2; ++n) {
        accS[m][n] = __builtin_amdgcn_mfma_f32_16x16x32_bf16(aF, bF[n],  accS[m][n], 0, 0, 0);
        accN[m][n] = __builtin_amdgcn_mfma_f32_16x16x32_bf16(aN, bF[n],  accN[m][n], 0, 0, 0);
        accD[m][n] = __builtin_amdgcn_mfma_f32_16x16x32_bf16(aD, bF2[n], accD[m][n], 0, 0, 0);
      }
    }
  }

  float sum = 0.f;
  const int r4 = (lane >> 4) * 4;
  const int cc = lane & 15;
#pragma unroll
  for (int m = 0; m < 4; ++m) {
    const int gi_base = i0 + wm * 64 + m * 16 + r4;
#pragma unroll
    for (int jj = 0; jj < 4; ++jj) {
      const int gi = gi_base + jj;
      const float rni = rn_i[gi];
#pragma unroll
      for (int n = 0; n < 2; ++n) {
        const int gj = j0 + wn * 32 + n * 16 + cc;
        const float sfull = accS[m][n][jj];
        const float num   = accN[m][n][jj];
        const float nd    = accD[m][n][jj];
        const float rnij  = rsqrtf(fmaxf(nd, 1e-24f));
        const float sim   = num * rni * rnij;
        const float d     = fabsf(sfull - sim);
        if (gi != gj) sum += d;
      }
    }
  }
  for (int off = 32; off > 0; off >>= 1) sum += __shfl_down(sum, off);
  if (lane == 0) red[wv] = sum;
  __syncthreads();
  if (t == 0) {
    float bs = 0.f;
    for (int w = 0; w < 8; ++w) bs += red[w];
    const float scale = 1.0f / (8192.0f * 8191.0f);
    atomicAdd(out, bs * scale);
  }
}

extern "C" void kernel_launch(void* const* d_in, const int* in_sizes, int n_in,
                              void* d_out, int out_size, void* d_ws, size_t ws_size,
                              hipStream_t stream) {
  const float* f    = (const float*)d_in[0];   // full_emb [8192,768] fp32
  const float* mask = (const float*)d_in[1];   // query_mask [8192,768] fp32
  float* out = (float*)d_out;                  // scalar loss

  const size_t need = 4 * PANEL_BYTES + (size_t)B_ROWS * sizeof(float);
  if (ws_size >= need) {
    unsigned char* pF   = (unsigned char*)d_ws;
    unsigned char* pFM2 = pF + PANEL_BYTES;
    unsigned char* pM2  = pFM2 + PANEL_BYTES;
    unsigned char* pF2  = pM2 + PANEL_BYTES;
    float* rn = (float*)(pF2 + PANEL_BYTES);
    hipMemsetAsync(rn, 0, B_ROWS * sizeof(float), stream);
    hipMemsetAsync(out, 0, sizeof(float), stream);
    convert_kernel<<<(B_ROWS * (D_DIM / 8)) / 256, 256, 0, stream>>>(
        f, mask, pF, pFM2, pM2, pF2, rn);
    fused_loss_mx_kernel<<<2048, NTHREADS, 0, stream>>>(pF, pFM2, pM2, pF2, rn, out);
  } else {
    float* rn_i = (float*)d_ws;
    rownorm_zero_kernel<<<B_ROWS / 4, 256, 0, stream>>>(f, mask, rn_i, out);
    dim3 grid(B_ROWS / 128, B_ROWS / 128);
    fused_loss_kernel<<<grid, NTHREADS, 0, stream>>>(f, mask, rn_i, out);
  }
}